// Round 10
// baseline (166.078 us; speedup 1.0000x reference)
//
#include <hip/hip_runtime.h>

// KNN argmin over L2, round 29: grid-strided low-WG versions of the three
// PROVEN bodies (R22 prep, R25 LDS phaseA, R21 phaseB).
//
// Model correction (fits ALL rounds +-2us): total = sum(true durs) + ~45us
// fixed per-run. The "48.5us/dispatch floor" was top-5 truncation. True
// durs: prep~9 (512 WG), phaseA~43 (2048 WG), phaseB~49 (4096 WG) -- each
// ~proportional to WAVE COUNT (~3ns/wave) and far above real work (phaseA
// MFMA ~4us; phaseB ~1.1 rescore items/query since eps~0.3 << key
// spacing). R28's fused K1 regressed (67 vs 52) via redundant per-y-tile
// cvt + aux stragglers; fusion abandoned, dispatch count is free.
//
// R29 lever: fewer, bigger WGs. prep: 256 WG x 2 units. phaseA: (32,16)
// WG x 4 q-tiles. phaseB: 512 WG x 8 query-groups. Bodies verbatim
// (barriers already guard LDS reuse across iterations) => absmax 0.
//
// Certificate unchanged: c=2^-9*1.01<=0.002, eps=0.004|q|^2+0.05; bmin
// encodes 0.998|s|^2 - 2*cross_f16 via cinit=-0.499|s|^2 (sqSc, same RNE
// mul). Blocks with bmin <= min+eps provably contain the true first
// argmin.
//
// Ledger: R19 153.3 | R20 153.0 | R21 145.8 | R22 148.3 | R23 314.8
// (spills) | R24 153.1 | R25 145.8 | R26 221.7 (uncoalesced) | R27 203.9
// (LDS conflicts) | R28 160.7 (K1 fusion regression; conflicts 0 ✓).
// Prediction: total ~100-115; phaseB 25-32, phaseA 20-28 visible in
// top-5. phaseB >=45 at 512 WGs falsifies the wave-launch-rate theory.

#define NTOT   16384
#define DIM    64
#define EPS_COEF 0.004f   // 2c with c=0.002 (>= 2^-9*1.01)
#define EPS_ABS  0.05f
#define CINIT_COEF (-0.499f)  // -(1-c)/2
#define FLT_BIG 3.4e38f

typedef __attribute__((ext_vector_type(8))) short short8;
typedef __attribute__((ext_vector_type(4))) float float4v;

__device__ __forceinline__ ushort f16_bits(float x) {
  union { _Float16 f; ushort u; } c;
  c.f = (_Float16)x;  // v_cvt_f16_f32, RNE
  return c.u;
}

// Opaque def: forbids rematerialization (forces register residency).
__device__ __forceinline__ void pin8(short8& v) {
  asm volatile("" : "+v"(v));
}

#define MFMA16F(A, B, C) __builtin_amdgcn_mfma_f32_16x16x32_f16(A, B, C, 0, 0, 0)

// ---------------------------------------------------------------------------
// Prep (R22 body, grid-strided): 256 WGs x 2 units. Unit u<256 -> S side
// (f16 panel + sqS + sqSc + S_T); u>=256 -> Q side (panel + sqQ).
// Panel layout (R8-proven):
//   off(r,k) = (r>>4)*1024 + (k>>5)*512 + (((k&31)>>3)*16 + (r&15))*8 + (k&7)
__global__ __launch_bounds__(256) void k_prep(
    const float* __restrict__ S, const float* __restrict__ Q,
    ushort* __restrict__ Sh, ushort* __restrict__ Qh,
    float* __restrict__ sqS, float* __restrict__ sqQ,
    float* __restrict__ sqSc, float* __restrict__ S_T) {
  __shared__ float tile[64][65];
  const int tid = threadIdx.x;

  for (int it = 0; it < 2; ++it) {
    const int u = blockIdx.x + it * 256;
    const bool isS = u < 256;
    const int rbase = (u & 255) * 64;
    const float* __restrict__ src = isS ? S : Q;
    ushort* __restrict__ dh = isS ? Sh : Qh;

    const int tx = tid & 63;
    const int ty = tid >> 6;
#pragma unroll
    for (int i = 0; i < 16; ++i) {
      const int r = i * 4 + ty;
      tile[r][tx] = src[(size_t)(rbase + r) * DIM + tx];  // coalesced
    }
    __syncthreads();

    if (isS) {  // transposed copy (coalesced, pad-safe)
#pragma unroll
      for (int i = 0; i < 16; ++i) {
        const int d = i * 4 + ty;
        S_T[(size_t)d * NTOT + rbase + tx] = tile[tx][d];
      }
    }

    // Panel-swizzled f16; stores are lane-contiguous 16B.
    const int panel = tid >> 6;           // 0..3
    const int half = (tid >> 5) & 1;      // k-half
    const int slot0 = (tid & 31) * 2;     // slot = q8*16 + m
#pragma unroll
    for (int ss = 0; ss < 2; ++ss) {
      const int s = slot0 + ss;
      const int m = s & 15;
      const int q8 = s >> 4;
      const int row = panel * 16 + m;
      const int kb = half * 32 + q8 * 8;
      short8 hv;
#pragma unroll
      for (int j = 0; j < 8; ++j) hv[j] = (short)f16_bits(tile[row][kb + j]);
      const size_t goff = (size_t)((rbase >> 4) + panel) * 1024 +
                          (size_t)half * 512 + (size_t)s * 8;
      *(short8*)&dh[goff] = hv;
    }

    // Row sum of squares (+ pre-scaled C-init on the S side).
    if (tid < 64) {
      float acc = 0.0f;
#pragma unroll
      for (int d = 0; d < DIM; ++d) {
        const float v = tile[tid][d];
        acc = fmaf(v, v, acc);
      }
      if (isS) {
        sqS[rbase + tid] = acc;
        sqSc[rbase + tid] = CINIT_COEF * acc;  // same v_mul RNE as before
      } else {
        sqQ[rbase + tid] = acc;
      }
    }
    __syncthreads();  // tile reuse safety for the next unit
  }
}

// ---------------------------------------------------------------------------
// Phase A (R25 body, grid-strided): grid (32 splits, 16) x 4 q-tiles.
// Block = 256 queries x 512 supports per iteration; 4 waves share the
// support panel via LDS (double-buffered 64-support chunks staged with
// global_load_lds width=16, linear dest, R8 lane-contiguous layout).
template <int BST>  // 16-support steps per bmin block: 8 -> SBLK=128
__global__ __launch_bounds__(256, 4) void k_phaseA(
    const ushort* __restrict__ Sh, const ushort* __restrict__ Qh,
    const float* __restrict__ sqSc, float* __restrict__ bmin) {
  constexpr int NSB = NTOT / (16 * BST);   // 128 or 64
  constexpr int SBLK = 16 * BST;
  __shared__ ushort spanel[2][4096];       // 2 x 8KB: 64 supports each
  __shared__ float ssq[2][64];

  const int tid = threadIdx.x;
  const int l = tid & 63;
  const int w = tid >> 6;
  const int lm = l & 15;
  const int lq = l >> 4;
  const int split = blockIdx.x;            // 0..31
  const int sbase = split * 512;

  // Async stage of chunk c into buffer b (loop-invariant; defined once).
  auto stage = [&](int c, int b) {
    const ushort* gs = Sh + ((size_t)(split * 32 + c * 4)) * 1024 +
                       (size_t)w * 1024 + (size_t)l * 8;
    ushort* ls = &spanel[b][w * 1024];
    __builtin_amdgcn_global_load_lds(
        (const __attribute__((address_space(1))) void*)(const void*)gs,
        (__attribute__((address_space(3))) void*)(void*)ls, 16, 0, 0);
    __builtin_amdgcn_global_load_lds(
        (const __attribute__((address_space(1))) void*)(const void*)(gs + 512),
        (__attribute__((address_space(3))) void*)(void*)(ls + 512), 16, 0, 0);
    if (tid < 16)
      *(float4*)&ssq[b][tid * 4] =
          *(const float4*)&sqSc[sbase + c * 64 + tid * 4];
  };

  for (int qt = 0; qt < 4; ++qt) {
    const int qbase = (blockIdx.y * 4 + qt) * 256 + w * 64;

    // Query (B) fragments: 4 tiles x 2 k-chunks, pinned (32 VGPR).
    short8 qh[4][2];
#pragma unroll
    for (int t = 0; t < 4; ++t) {
      const size_t pb = (size_t)((qbase >> 4) + t) * 1024 + (size_t)l * 8;
      qh[t][0] = *(const short8*)&Qh[pb];
      qh[t][1] = *(const short8*)&Qh[pb + 512];
    }
#pragma unroll
    for (int t = 0; t < 4; ++t) {
      pin8(qh[t][0]);
      pin8(qh[t][1]);
    }

    float bmr[4] = {-FLT_BIG, -FLT_BIG, -FLT_BIG, -FLT_BIG};

    stage(0, 0);
    __syncthreads();  // vmcnt(0) drain: chunk 0 resident

    for (int c = 0; c < 8; ++c) {
      const int b = c & 1;
      if (c + 1 < 8) stage(c + 1, b ^ 1);  // async issue before compute

#pragma unroll
      for (int st = 0; st < 4; ++st) {
        const short8 h0 = *(const short8*)&spanel[b][st * 1024 + l * 8];
        const short8 h1 = *(const short8*)&spanel[b][st * 1024 + 512 + l * 8];
        const float4 sqv = *(const float4*)&ssq[b][st * 16 + lq * 4];
        float4v cinit;
        cinit[0] = sqv.x;
        cinit[1] = sqv.y;
        cinit[2] = sqv.z;
        cinit[3] = sqv.w;
#pragma unroll
        for (int t = 0; t < 4; ++t) {
          float4v a = MFMA16F(h0, qh[t][0], cinit);
          a = MFMA16F(h1, qh[t][1], a);
          // v_max3(a0,a1,a2) + max(a3,bmr) + max. Exact (assoc/comm).
          bmr[t] = fmaxf(fmaxf(fmaxf(a[0], a[1]), a[2]), fmaxf(a[3], bmr[t]));
        }
      }

      if ((((c + 1) * 4) & (BST - 1)) == 0) {  // finished a bmin block
        const int gb = split * (512 / SBLK) + ((c + 1) * 64 / SBLK) - 1;
#pragma unroll
        for (int t = 0; t < 4; ++t) {
          float v = bmr[t];
          v = fmaxf(v, __shfl_xor(v, 16, 64));
          v = fmaxf(v, __shfl_xor(v, 32, 64));
          if (lq == 0)
            bmin[(size_t)(qbase + t * 16 + lm) * NSB + gb] = -2.0f * v;
          bmr[t] = -FLT_BIG;
        }
      }
      __syncthreads();  // drains stage(c+1) + guards buffer reuse
    }
    // trailing barrier above also guards spanel reuse by the next q-tile
  }
}

// ---------------------------------------------------------------------------
// Phase B (R21 body, grid-strided): 512 WGs x 8 query-groups. Per group:
// 4 queries (one per wave), within-block work stealing + register-staged
// S_T rescore. Exact fp32 keys, row-ascending accumulation; strict-<
// ascending per lane + lexicographic merges => np.argmin first-index.
template <int SBLK>
__global__ __launch_bounds__(256, 3) void k_phaseB(
    const float* __restrict__ S_T,   // [64][NTOT]
    const float* __restrict__ Q,     // [NTOT][64]
    const float* __restrict__ sqS, const float* __restrict__ sqQ,
    const float* __restrict__ bmin,
    const float* __restrict__ onehot, float* __restrict__ out) {
  constexpr int NSB = NTOT / SBLK;    // 128 or 64
  constexpr int NB64 = NSB / 64;
  constexpr int SPL = SBLK / 64;      // supports per lane: 2 or 4

  __shared__ float sQrow[4][64];
  __shared__ unsigned long long smask[4][NB64];
  __shared__ float sbk[4][4];
  __shared__ int sbi[4][4];

  const int lane = threadIdx.x & 63;
  const int w = threadIdx.x >> 6;

  for (int it = 0; it < 8; ++it) {
    const int ublk = blockIdx.x * 8 + it;
    const int q = ublk * 4 + w;

    __syncthreads();  // guards LDS reuse across iterations

    if (lane < 16)
      *(float4*)&sQrow[w][lane * 4] =
          *(const float4*)&Q[(size_t)q * DIM + lane * 4];

    // Per-query certified filter width.
    const float eps = EPS_COEF * sqQ[q] + EPS_ABS;

    float bv[NB64];
#pragma unroll
    for (int j = 0; j < NB64; ++j)
      bv[j] = bmin[(size_t)q * NSB + j * 64 + lane];
    float m = bv[0];
#pragma unroll
    for (int j = 1; j < NB64; ++j) m = fminf(m, bv[j]);
#pragma unroll
    for (int d = 1; d < 64; d <<= 1) m = fminf(m, __shfl_xor(m, d, 64));
    const float thr = m + eps;

#pragma unroll
    for (int j = 0; j < NB64; ++j) {
      const unsigned long long msk = __ballot(bv[j] <= thr);
      if (lane == 0) smask[w][j] = msk;
    }
    __syncthreads();  // sQrow + smask visible block-wide

    // Round-robin the combined worklist (ascending block order per query
    // => per-lane ascending support index => strict-< keeps FIRST min).
    int idx = 0;
    for (int qq = 0; qq < 4; ++qq) {
      float bkq = FLT_BIG;
      int biq = 0;
      for (int j = 0; j < NB64; ++j) {
        unsigned long long msk = smask[qq][j];  // uniform broadcast read
        while (msk) {  // wave-uniform control
          const int b = j * 64 + (__ffsll((long long)msk) - 1);
          msk &= msk - 1;
          if ((idx++ & 3) != w) continue;
          const int s0 = b * SBLK + lane * SPL;
          if (SPL == 2) {
            // Register-staged: 2 halves x {32 float2 loads -> 64 fmaf}.
            float a0 = 0.f, a1 = 0.f;
#pragma unroll
            for (int h = 0; h < 2; ++h) {
              float2 x[32];
#pragma unroll
              for (int d = 0; d < 32; ++d)
                x[d] = *(const float2*)&S_T[(size_t)(h * 32 + d) * NTOT + s0];
#pragma unroll
              for (int d = 0; d < 32; ++d) {
                const float qd = sQrow[qq][h * 32 + d];
                a0 = fmaf(qd, x[d].x, a0);
                a1 = fmaf(qd, x[d].y, a1);
              }
            }
            const float2 sq2 = *(const float2*)&sqS[s0];
            const float k0 = fmaf(-2.f, a0, sq2.x);
            const float k1 = fmaf(-2.f, a1, sq2.y);
            bool u;  // ascending index, strict < => first min per lane
            u = k0 < bkq; bkq = u ? k0 : bkq; biq = u ? s0 : biq;
            u = k1 < bkq; bkq = u ? k1 : bkq; biq = u ? (s0 + 1) : biq;
          } else {
            // Register-staged: 4 quarters x {16 float4 loads -> 64 fmaf}.
            float a0 = 0.f, a1 = 0.f, a2 = 0.f, a3 = 0.f;
#pragma unroll
            for (int hh = 0; hh < 4; ++hh) {
              float4 x[16];
#pragma unroll
              for (int d = 0; d < 16; ++d)
                x[d] = *(const float4*)&S_T[(size_t)(hh * 16 + d) * NTOT + s0];
#pragma unroll
              for (int d = 0; d < 16; ++d) {
                const float qd = sQrow[qq][hh * 16 + d];
                a0 = fmaf(qd, x[d].x, a0);
                a1 = fmaf(qd, x[d].y, a1);
                a2 = fmaf(qd, x[d].z, a2);
                a3 = fmaf(qd, x[d].w, a3);
              }
            }
            const float4 sq4 = *(const float4*)&sqS[s0];
            const float k0 = fmaf(-2.f, a0, sq4.x);
            const float k1 = fmaf(-2.f, a1, sq4.y);
            const float k2 = fmaf(-2.f, a2, sq4.z);
            const float k3 = fmaf(-2.f, a3, sq4.w);
            bool u;
            u = k0 < bkq; bkq = u ? k0 : bkq; biq = u ? s0 : biq;
            u = k1 < bkq; bkq = u ? k1 : bkq; biq = u ? (s0 + 1) : biq;
            u = k2 < bkq; bkq = u ? k2 : bkq; biq = u ? (s0 + 2) : biq;
            u = k3 < bkq; bkq = u ? k3 : bkq; biq = u ? (s0 + 3) : biq;
          }
        }
      }
      // Cross-lane lexicographic argmin on exact keys => first-index.
#pragma unroll
      for (int d = 1; d < 64; d <<= 1) {
        const float ok = __shfl_xor(bkq, d, 64);
        const int oi = __shfl_xor(biq, d, 64);
        const bool u = (ok < bkq) || (ok == bkq && oi < biq);
        bkq = u ? ok : bkq;
        biq = u ? oi : biq;
      }
      if (lane == 0) { sbk[qq][w] = bkq; sbi[qq][w] = biq; }
    }
    __syncthreads();

    // Wave w: lexicographic merge of the 4 wave partials for query w.
    float fk = sbk[w][0];
    int fi = sbi[w][0];
#pragma unroll
    for (int ww = 1; ww < 4; ++ww) {
      const float ok = sbk[w][ww];
      const int oi = sbi[w][ww];
      const bool u = (ok < fk) || (ok == fk && oi < fi);
      fk = u ? ok : fk;
      fi = u ? oi : fi;
    }

    // Label: one-hot rows exact {0,1}; first 1 == np.argmax.
    const float ov = onehot[(size_t)fi * 64 + lane];
    const unsigned long long lmask = __ballot(ov > 0.5f);
    const int label = __ffsll((long long)lmask) - 1;
    out[(size_t)q * 64 + lane] = (lane == label) ? 1.0f : 0.0f;
  }
}

// ---------------------------------------------------------------------------
extern "C" void kernel_launch(void* const* d_in, const int* in_sizes, int n_in,
                              void* d_out, int out_size, void* d_ws, size_t ws_size,
                              hipStream_t stream) {
  const float* S = (const float*)d_in[0];   // [16384][64]
  const float* Q = (const float*)d_in[1];   // [16384][64]
  const float* OH = (const float*)d_in[2];  // [16384][64]
  float* out = (float*)d_out;

  char* ws = (char*)d_ws;
  ushort* Sh = (ushort*)ws;                                  // [0, 2MB)
  ushort* Qh = (ushort*)(ws + (2u << 20));                   // [2, 4MB)
  float* S_T = (float*)(ws + (4u << 20));                    // [4, 8MB)
  float* sqS = (float*)(ws + (8u << 20));                    // 64 KB
  float* sqQ = (float*)(ws + (8u << 20) + (64u << 10));      // 64 KB
  float* sqSc = (float*)(ws + (8u << 20) + (128u << 10));    // 64 KB
  float* bmin = (float*)(ws + (8u << 20) + (192u << 10));    // up to 8 MB

  k_prep<<<dim3(256), 256, 0, stream>>>(S, Q, Sh, Qh, sqS, sqQ, sqSc, S_T);

  // 128-granular bmin (8 MB) if workspace allows; else 256-granular (4 MB).
  if (ws_size >= (17u << 20)) {
    k_phaseA<8><<<dim3(32, 16), 256, 0, stream>>>(Sh, Qh, sqSc, bmin);
    k_phaseB<128><<<dim3(512), 256, 0, stream>>>(S_T, Q, sqS, sqQ,
                                                 bmin, OH, out);
  } else {
    k_phaseA<16><<<dim3(32, 16), 256, 0, stream>>>(Sh, Qh, sqSc, bmin);
    k_phaseB<256><<<dim3(512), 256, 0, stream>>>(S_T, Q, sqS, sqQ,
                                                 bmin, OH, out);
  }
  (void)in_sizes; (void)n_in; (void)out_size; (void)ws_size;
}